// Round 2
// baseline (428.252 us; speedup 1.0000x reference)
//
#include <hip/hip_runtime.h>
#include <hip/hip_bf16.h>

// RotaryMultiheadAttention: B=2,S=2048,E=1024,H=16,D=64
// d_out is FP32: [output (B,S,E)] ++ [attn_weights (B,H,S,S)]
// Precision: split-bf16 (hi+lo) GEMMs on Q-proj, K-proj, QK^T; plain bf16 for V/PV/O.
// ws usage ~106 MB.

#define DEV static __device__ __forceinline__

typedef __attribute__((ext_vector_type(8))) short short8;
typedef __attribute__((ext_vector_type(4))) float f32x4;
typedef unsigned short u16;

DEV u16 f2bf(float x){
  unsigned u = __float_as_uint(x);
  u += 0x7fff + ((u >> 16) & 1);           // RNE
  return (u16)(u >> 16);
}
DEV float bf2f(u16 h){ return __uint_as_float(((unsigned)h) << 16); }

#define MFMA(a,b,c) __builtin_amdgcn_mfma_f32_16x16x32_bf16((a),(b),(c),0,0,0)

#define LDP 72   // padded LDS row stride (bf16 elems) for [*][64] tiles: 144B/row -> 2-way conflicts max

// ---------------- prep: fp32 -> bf16 hi (+ optional lo residual) ----------------
__global__ void k_convert(const float* __restrict__ src, u16* __restrict__ hi,
                          u16* __restrict__ lo, int n4){
  int i = blockIdx.x * blockDim.x + threadIdx.x;
  int st = gridDim.x * blockDim.x;
  for (; i < n4; i += st){
    float4 v = ((const float4*)src)[i];
    u16 h0=f2bf(v.x), h1=f2bf(v.y), h2=f2bf(v.z), h3=f2bf(v.w);
    ushort4 o; o.x=h0; o.y=h1; o.z=h2; o.w=h3;
    ((ushort4*)hi)[i] = o;
    if (lo){
      ushort4 p;
      p.x=f2bf(v.x-bf2f(h0)); p.y=f2bf(v.y-bf2f(h1));
      p.z=f2bf(v.z-bf2f(h2)); p.w=f2bf(v.w-bf2f(h3));
      ((ushort4*)lo)[i] = p;
    }
  }
}

// ---------------- RoPE cos/sin table: cs[0:65536]=cos, cs[65536:]=sin ----------------
__global__ void k_cossin(float* __restrict__ cs){
  int t = blockIdx.x * blockDim.x + threadIdx.x;
  if (t >= 2048*32) return;
  int s = t >> 5, i = t & 31;
  float f = powf(10000.0f, -(float)i * (1.0f/32.0f));
  float ang = (float)s * f;
  cs[t]         = cosf(ang);
  cs[65536 + t] = sinf(ang);
}

// ---------------- fused projection (+RoPE, +scale, or +transpose for V) ----------------
// MODE 0: q = rope(x@Wq^T + b) * 0.125 -> out_hi/out_lo [B,H,S,D]  (split GEMM)
// MODE 1: k = rope(x@Wk^T + b)         -> out_hi/out_lo [B,H,S,D]  (split GEMM)
// MODE 2: v = x@Wv^T + b               -> out_hi = vT [B,H,D,S]    (plain GEMM)
template<int MODE>
__global__ __launch_bounds__(256, 2) void k_proj(
    const u16* __restrict__ Ah_g, const u16* __restrict__ Al_g,
    const u16* __restrict__ Wh_g, const u16* __restrict__ Wl_g,
    const float* __restrict__ bias, const float* __restrict__ cs,
    u16* __restrict__ out_hi, u16* __restrict__ out_lo)
{
  __shared__ __align__(16) u16 smem[4*128*LDP];
  u16* AhL = smem;
  u16* AlL = smem + 128*LDP;
  u16* BhL = smem + 2*128*LDP;
  u16* BlL = smem + 3*128*LDP;

  const int n0 = blockIdx.x * 128, m0 = blockIdx.y * 128;
  const int tid = threadIdx.x, lane = tid & 63, wv = tid >> 6;
  const int wm = wv >> 1, wn = wv & 1;
  const int l15 = lane & 15, l4 = lane >> 4;

  const f32x4 z4 = {0.f,0.f,0.f,0.f};
  f32x4 acc[4][4];
#pragma unroll
  for (int i=0;i<4;++i)
#pragma unroll
    for (int j=0;j<4;++j) acc[i][j] = z4;

  for (int kt = 0; kt < 16; ++kt){
    const int K0 = kt * 64;
#pragma unroll
    for (int c = 0; c < 4; ++c){
      int id = tid + 256*c;
      int row = id >> 3, col = (id & 7) * 8;
      *(short8*)&AhL[row*LDP + col] = *(const short8*)&Ah_g[(size_t)(m0+row)*1024 + K0 + col];
      *(short8*)&BhL[row*LDP + col] = *(const short8*)&Wh_g[(size_t)(n0+row)*1024 + K0 + col];
      if (MODE != 2){
        *(short8*)&AlL[row*LDP + col] = *(const short8*)&Al_g[(size_t)(m0+row)*1024 + K0 + col];
        *(short8*)&BlL[row*LDP + col] = *(const short8*)&Wl_g[(size_t)(n0+row)*1024 + K0 + col];
      }
    }
    __syncthreads();
#pragma unroll
    for (int ks = 0; ks < 2; ++ks){
      const int ko = l4*8 + ks*32;
      short8 ah[4], bh[4], al[4], bl[4];
#pragma unroll
      for (int mi=0;mi<4;++mi) ah[mi] = *(const short8*)&AhL[(wm*64+mi*16+l15)*LDP + ko];
#pragma unroll
      for (int nf=0;nf<4;++nf) bh[nf] = *(const short8*)&BhL[(wn*64+nf*16+l15)*LDP + ko];
      if (MODE != 2){
#pragma unroll
        for (int mi=0;mi<4;++mi) al[mi] = *(const short8*)&AlL[(wm*64+mi*16+l15)*LDP + ko];
#pragma unroll
        for (int nf=0;nf<4;++nf) bl[nf] = *(const short8*)&BlL[(wn*64+nf*16+l15)*LDP + ko];
      }
#pragma unroll
      for (int mi=0;mi<4;++mi)
#pragma unroll
        for (int nf=0;nf<4;++nf){
          acc[mi][nf] = MFMA(ah[mi], bh[nf], acc[mi][nf]);
          if (MODE != 2){
            acc[mi][nf] = MFMA(al[mi], bh[nf], acc[mi][nf]);
            acc[mi][nf] = MFMA(ah[mi], bl[nf], acc[mi][nf]);
          }
        }
    }
    __syncthreads();
  }

  if (MODE != 2){
    const int h = (n0 + wn*64) >> 6;   // wave covers exactly one head (64 cols, 64-aligned)
    float bv[4];
#pragma unroll
    for (int nf=0;nf<4;++nf) bv[nf] = bias[n0 + wn*64 + nf*16 + l15];
#pragma unroll
    for (int mi=0;mi<4;++mi)
#pragma unroll
      for (int r=0;r<4;++r){
        int srow = m0 + wm*64 + mi*16 + l4*4 + r;
        int b = srow >> 11, s = srow & 2047;
#pragma unroll
        for (int half=0; half<2; ++half){
          int dmod = half*16 + l15;                       // d (<32); partner d+32
          float ct = cs[s*32 + dmod], st = cs[65536 + s*32 + dmod];
          float vlo = acc[mi][half  ][r] + bv[half  ];    // q[d]
          float vhi = acc[mi][half+2][r] + bv[half+2];    // q[d+32]
          float olo = vlo*ct - vhi*st;                    // d<32: q*cos - q[d+32]*sin
          float ohi = vhi*ct + vlo*st;                    // d>=32: q*cos + q[d-32]*sin
          if (MODE == 0){ olo *= 0.125f; ohi *= 0.125f; } // bake 1/sqrt(D) into q
          size_t base = ((size_t)(b*16 + h)*2048 + s)*64;
          u16 hl = f2bf(olo), hh = f2bf(ohi);
          out_hi[base + dmod]      = hl;
          out_hi[base + dmod + 32] = hh;
          out_lo[base + dmod]      = f2bf(olo - bf2f(hl));
          out_lo[base + dmod + 32] = f2bf(ohi - bf2f(hh));
        }
      }
  } else {
    // V: bias add, then LDS transpose -> vT [B,H,D,S] (coalesced stores)
    u16* T = smem;   // [128][132]; safe: last loop iter ended with __syncthreads()
#pragma unroll
    for (int mi=0;mi<4;++mi)
#pragma unroll
      for (int nf=0;nf<4;++nf)
#pragma unroll
        for (int r=0;r<4;++r){
          int rowl = wm*64 + mi*16 + l4*4 + r;
          int coll = wn*64 + nf*16 + l15;
          T[rowl*132 + coll] = f2bf(acc[mi][nf][r] + bias[n0 + coll]);
        }
    __syncthreads();
    int col = tid >> 1, sh = tid & 1;
    int h = (n0 + col) >> 6, d = (n0 + col) & 63;
    int b = m0 >> 11;
    size_t gbase = ((size_t)(b*16 + h)*64 + d)*2048 + (m0 & 2047) + sh*64;
#pragma unroll
    for (int j=0;j<64;j+=8){
      short8 pk;
#pragma unroll
      for (int e=0;e<8;++e) pk[e] = (short)T[(sh*64 + j + e)*132 + col];
      *(short8*)&out_hi[gbase + j] = pk;
    }
  }
}

// ---------------- attention: two-pass (pass1 approx row-sums; pass2 precise z, w, PV) ----------------
__global__ __launch_bounds__(256, 2) void k_attn(
    const u16* __restrict__ qh, const u16* __restrict__ ql,
    const u16* __restrict__ kh, const u16* __restrict__ kl,
    const u16* __restrict__ vt,
    float* __restrict__ wout,  // d_out attn weights [B,H,S,S]  (FP32)
    u16* __restrict__ aout)    // attn output [B,S,H,D] (bf16, internal)
{
  __shared__ __align__(16) u16 KhL[64*LDP], KlL[64*LDP], VtL[64*LDP], WL[128*LDP];
  __shared__ float lpart[2][128];
  __shared__ float invl[128];

  const int m0 = blockIdx.x * 128;
  const int h = blockIdx.y, b = blockIdx.z;
  const size_t bh = (size_t)(b*16 + h);
  const u16* qh_p = qh + bh*2048*64;
  const u16* ql_p = ql + bh*2048*64;
  const u16* kh_p = kh + bh*2048*64;
  const u16* kl_p = kl + bh*2048*64;
  const u16* vt_p = vt + bh*64*2048;

  const int tid = threadIdx.x, lane = tid & 63, wv = tid >> 6;
  const int wm = wv >> 1, wn = wv & 1;
  const int l15 = lane & 15, l4 = lane >> 4;
  const f32x4 z4 = {0.f,0.f,0.f,0.f};

  // Q fragments resident in registers (hi+lo), q pre-scaled by 1/8 with RoPE applied
  short8 qhf[4][2], qlf[4][2];
#pragma unroll
  for (int mi=0;mi<4;++mi)
#pragma unroll
    for (int ks=0;ks<2;++ks){
      size_t off = (size_t)(m0 + wm*64 + mi*16 + l15)*64 + l4*8 + ks*32;
      qhf[mi][ks] = *(const short8*)&qh_p[off];
      qlf[mi][ks] = *(const short8*)&ql_p[off];
    }

  float lsum[4][4];
#pragma unroll
  for (int mi=0;mi<4;++mi)
#pragma unroll
    for (int r=0;r<4;++r) lsum[mi][r] = 0.f;

  // ---- pass 1: row sums of exp(z~) using hi*hi only (softmax denom tolerates ~3e-3 logit err) ----
  for (int jt = 0; jt < 32; ++jt){
    const int j0 = jt*64;
#pragma unroll
    for (int c=0;c<2;++c){
      int id = tid + 256*c;
      int row = id >> 3, col = (id & 7)*8;
      *(short8*)&KhL[row*LDP + col] = *(const short8*)&kh_p[(size_t)(j0+row)*64 + col];
    }
    __syncthreads();
    f32x4 zf[4][2];
#pragma unroll
    for (int mi=0;mi<4;++mi){ zf[mi][0]=z4; zf[mi][1]=z4; }
#pragma unroll
    for (int ks=0;ks<2;++ks){
      const int ko = l4*8 + ks*32;
      short8 kb0 = *(const short8*)&KhL[(wn*32      + l15)*LDP + ko];
      short8 kb1 = *(const short8*)&KhL[(wn*32 + 16 + l15)*LDP + ko];
#pragma unroll
      for (int mi=0;mi<4;++mi){
        zf[mi][0] = MFMA(qhf[mi][ks], kb0, zf[mi][0]);
        zf[mi][1] = MFMA(qhf[mi][ks], kb1, zf[mi][1]);
      }
    }
#pragma unroll
    for (int mi=0;mi<4;++mi)
#pragma unroll
      for (int r=0;r<4;++r){
        float p = __expf(fminf(zf[mi][0][r], 60.f)) + __expf(fminf(zf[mi][1][r], 60.f));
        p += __shfl_xor(p, 1, 64);
        p += __shfl_xor(p, 2, 64);
        p += __shfl_xor(p, 4, 64);
        p += __shfl_xor(p, 8, 64);
        lsum[mi][r] += p;
      }
    __syncthreads();
  }
  if (l15 == 0){
#pragma unroll
    for (int mi=0;mi<4;++mi)
#pragma unroll
      for (int r=0;r<4;++r)
        lpart[wn][wm*64 + mi*16 + l4*4 + r] = lsum[mi][r];
  }
  __syncthreads();
  if (tid < 128) invl[tid] = 1.0f / (lpart[0][tid] + lpart[1][tid]);
  __syncthreads();

  // ---- pass 2: precise z (3-term split), write w (fp32 direct), accumulate PV ----
  f32x4 oacc[4][2];
#pragma unroll
  for (int mi=0;mi<4;++mi){ oacc[mi][0]=z4; oacc[mi][1]=z4; }

  for (int jt = 0; jt < 32; ++jt){
    const int j0 = jt*64;
#pragma unroll
    for (int c=0;c<2;++c){
      int id = tid + 256*c;
      int row = id >> 3, col = (id & 7)*8;
      *(short8*)&KhL[row*LDP + col] = *(const short8*)&kh_p[(size_t)(j0+row)*64 + col];
      *(short8*)&KlL[row*LDP + col] = *(const short8*)&kl_p[(size_t)(j0+row)*64 + col];
      *(short8*)&VtL[row*LDP + col] = *(const short8*)&vt_p[(size_t)row*2048 + j0 + col];
    }
    __syncthreads();
    f32x4 zf[4][2];
#pragma unroll
    for (int mi=0;mi<4;++mi){ zf[mi][0]=z4; zf[mi][1]=z4; }
#pragma unroll
    for (int ks=0;ks<2;++ks){
      const int ko = l4*8 + ks*32;
      short8 kbh[2], kbl[2];
#pragma unroll
      for (int nf=0;nf<2;++nf){
        kbh[nf] = *(const short8*)&KhL[(wn*32 + nf*16 + l15)*LDP + ko];
        kbl[nf] = *(const short8*)&KlL[(wn*32 + nf*16 + l15)*LDP + ko];
      }
#pragma unroll
      for (int mi=0;mi<4;++mi)
#pragma unroll
        for (int nf=0;nf<2;++nf){
          zf[mi][nf] = MFMA(qhf[mi][ks], kbh[nf], zf[mi][nf]);
          zf[mi][nf] = MFMA(qlf[mi][ks], kbh[nf], zf[mi][nf]);
          zf[mi][nf] = MFMA(qhf[mi][ks], kbl[nf], zf[mi][nf]);
        }
    }
#pragma unroll
    for (int mi=0;mi<4;++mi)
#pragma unroll
      for (int r=0;r<4;++r){
        int rowl = wm*64 + mi*16 + l4*4 + r;
        float il = invl[rowl];
        size_t gr = (bh*2048 + (size_t)(m0 + rowl))*2048 + j0;
#pragma unroll
        for (int nf=0;nf<2;++nf){
          float w = __expf(fminf(zf[mi][nf][r], 60.f)) * il;
          WL[rowl*LDP + wn*32 + nf*16 + l15] = f2bf(w);   // bf16 copy for PV
          wout[gr + wn*32 + nf*16 + l15] = w;             // fp32 to d_out (64B/16-lane seg)
        }
      }
    __syncthreads();
#pragma unroll
    for (int ks=0;ks<2;++ks){   // PV: O += w * V
      const int ko = l4*8 + ks*32;
      short8 aw[4], bvv[2];
#pragma unroll
      for (int mi=0;mi<4;++mi) aw[mi] = *(const short8*)&WL[(wm*64 + mi*16 + l15)*LDP + ko];
#pragma unroll
      for (int nf=0;nf<2;++nf) bvv[nf] = *(const short8*)&VtL[(wn*32 + nf*16 + l15)*LDP + ko];
#pragma unroll
      for (int mi=0;mi<4;++mi)
#pragma unroll
        for (int nf=0;nf<2;++nf)
          oacc[mi][nf] = MFMA(aw[mi], bvv[nf], oacc[mi][nf]);
    }
    __syncthreads();
  }

#pragma unroll
  for (int mi=0;mi<4;++mi)
#pragma unroll
    for (int nf=0;nf<2;++nf)
#pragma unroll
      for (int r=0;r<4;++r){
        int rowl = wm*64 + mi*16 + l4*4 + r;
        int d = wn*32 + nf*16 + l15;
        aout[((size_t)(b*2048 + m0 + rowl)*16 + h)*64 + d] = f2bf(oacc[mi][nf][r]);
      }
}

// ---------------- output projection: out0 = attn_out @ Wo^T + bo (plain bf16, fp32 store) ----------------
__global__ __launch_bounds__(256, 2) void k_oproj(
    const u16* __restrict__ A_g, const u16* __restrict__ W_g,
    const float* __restrict__ bias, float* __restrict__ out0)
{
  __shared__ __align__(16) u16 AhL[128*LDP];
  __shared__ __align__(16) u16 BhL[128*LDP];
  const int n0 = blockIdx.x * 128, m0 = blockIdx.y * 128;
  const int tid = threadIdx.x, lane = tid & 63, wv = tid >> 6;
  const int wm = wv >> 1, wn = wv & 1, l15 = lane & 15, l4 = lane >> 4;
  const f32x4 z4 = {0.f,0.f,0.f,0.f};
  f32x4 acc[4][4];
#pragma unroll
  for (int i=0;i<4;++i)
#pragma unroll
    for (int j=0;j<4;++j) acc[i][j] = z4;

  for (int kt = 0; kt < 16; ++kt){
    const int K0 = kt * 64;
#pragma unroll
    for (int c = 0; c < 4; ++c){
      int id = tid + 256*c;
      int row = id >> 3, col = (id & 7) * 8;
      *(short8*)&AhL[row*LDP + col] = *(const short8*)&A_g[(size_t)(m0+row)*1024 + K0 + col];
      *(short8*)&BhL[row*LDP + col] = *(const short8*)&W_g[(size_t)(n0+row)*1024 + K0 + col];
    }
    __syncthreads();
#pragma unroll
    for (int ks = 0; ks < 2; ++ks){
      const int ko = l4*8 + ks*32;
      short8 ah[4], bhh[4];
#pragma unroll
      for (int mi=0;mi<4;++mi) ah[mi] = *(const short8*)&AhL[(wm*64+mi*16+l15)*LDP + ko];
#pragma unroll
      for (int nf=0;nf<4;++nf) bhh[nf] = *(const short8*)&BhL[(wn*64+nf*16+l15)*LDP + ko];
#pragma unroll
      for (int mi=0;mi<4;++mi)
#pragma unroll
        for (int nf=0;nf<4;++nf)
          acc[mi][nf] = MFMA(ah[mi], bhh[nf], acc[mi][nf]);
    }
    __syncthreads();
  }
#pragma unroll
  for (int mi=0;mi<4;++mi)
#pragma unroll
    for (int nf=0;nf<4;++nf)
#pragma unroll
      for (int r=0;r<4;++r){
        int rowl = wm*64 + mi*16 + l4*4 + r;
        int coll = wn*64 + nf*16 + l15;
        out0[(size_t)(m0+rowl)*1024 + n0 + coll] = acc[mi][nf][r] + bias[n0+coll];
      }
}

// ---------------- launcher ----------------
extern "C" void kernel_launch(void* const* d_in, const int* in_sizes, int n_in,
                              void* d_out, int out_size, void* d_ws, size_t ws_size,
                              hipStream_t stream) {
  const float* query = (const float*)d_in[0];
  const float* key   = (const float*)d_in[1];
  const float* value = (const float*)d_in[2];
  const float* Wq = (const float*)d_in[3]; const float* bq = (const float*)d_in[4];
  const float* Wk = (const float*)d_in[5]; const float* bk = (const float*)d_in[6];
  const float* Wv = (const float*)d_in[7]; const float* bv = (const float*)d_in[8];
  const float* Wo = (const float*)d_in[9]; const float* bo = (const float*)d_in[10];

  float* out0 = (float*)d_out;                     // output (B,S,E), fp32
  float* out1 = out0 + (size_t)4096*1024;          // attn_weights (B,H,S,S), fp32

  char* cur = (char*)d_ws;
  auto take = [&](size_t bytes)->void*{
    void* p = (void*)cur; cur += (bytes + 255) & ~(size_t)255; return p;
  };
  u16* query_hi = (u16*)take(8388608);
  u16* query_lo = (u16*)take(8388608);
  u16* key_hi   = (u16*)take(8388608);
  u16* key_lo   = (u16*)take(8388608);
  u16* value_hi = (u16*)take(8388608);
  u16* Wq_hi = (u16*)take(2097152); u16* Wq_lo = (u16*)take(2097152);
  u16* Wk_hi = (u16*)take(2097152); u16* Wk_lo = (u16*)take(2097152);
  u16* Wv_hi = (u16*)take(2097152);
  u16* Wo_hi = (u16*)take(2097152);
  u16* q_hi = (u16*)take(8388608);  u16* q_lo = (u16*)take(8388608);
  u16* k_hi = (u16*)take(8388608);  u16* k_lo = (u16*)take(8388608);
  u16* vT   = (u16*)take(8388608);
  u16* attn_o = (u16*)take(8388608);
  float* cs = (float*)take(524288);
  // total ~106 MB of ws

  k_convert<<<1024, 256, 0, stream>>>(query, query_hi, query_lo, 1048576);
  k_convert<<<1024, 256, 0, stream>>>(key,   key_hi,   key_lo,   1048576);
  k_convert<<<1024, 256, 0, stream>>>(value, value_hi, nullptr,  1048576);
  k_convert<<<512,  256, 0, stream>>>(Wq, Wq_hi, Wq_lo, 262144);
  k_convert<<<512,  256, 0, stream>>>(Wk, Wk_hi, Wk_lo, 262144);
  k_convert<<<512,  256, 0, stream>>>(Wv, Wv_hi, nullptr, 262144);
  k_convert<<<512,  256, 0, stream>>>(Wo, Wo_hi, nullptr, 262144);
  k_cossin<<<256, 256, 0, stream>>>(cs);

  k_proj<0><<<dim3(8,32), 256, 0, stream>>>(query_hi, query_lo, Wq_hi, Wq_lo, bq, cs, q_hi, q_lo);
  k_proj<1><<<dim3(8,32), 256, 0, stream>>>(key_hi,   key_lo,   Wk_hi, Wk_lo, bk, cs, k_hi, k_lo);
  k_proj<2><<<dim3(8,32), 256, 0, stream>>>(value_hi, nullptr,  Wv_hi, nullptr, bv, nullptr, vT, nullptr);

  k_attn<<<dim3(16,16,2), 256, 0, stream>>>(q_hi, q_lo, k_hi, k_lo, vT, out1, attn_o);

  k_oproj<<<dim3(8,32), 256, 0, stream>>>(attn_o, Wo_hi, bo, out0);
}

// Round 3
// 375.594 us; speedup vs baseline: 1.1402x; 1.1402x over previous
//
#include <hip/hip_runtime.h>
#include <hip/hip_bf16.h>

// RotaryMultiheadAttention: B=2,S=2048,E=1024,H=16,D=64
// d_out FP32: [output (B,S,E)] ++ [attn_weights (B,H,S,S)]
// Numerics: 3-term split-bf16 Q/K projections (fp32 RoPE epilogue); q,k stored
// bf16 (hi only); 1-term bf16 QK^T (pass1 & pass2 identical z -> consistent
// softmax); bf16 V/PV/O.  Staging via global_load_lds(16B) + XOR-swizzle.

#define DEV static __device__ __forceinline__

typedef __attribute__((ext_vector_type(8))) short short8;
typedef __attribute__((ext_vector_type(4))) float f32x4;
typedef unsigned short u16;

#if defined(__has_builtin)
# if __has_builtin(__builtin_amdgcn_global_load_lds)
#  define HAS_GLL 1
# endif
#endif
#ifndef HAS_GLL
# define HAS_GLL 0
#endif

DEV u16 f2bf(float x){
  unsigned u = __float_as_uint(x);
  u += 0x7fff + ((u >> 16) & 1);           // RNE
  return (u16)(u >> 16);
}
DEV float bf2f(u16 h){ return __uint_as_float(((unsigned)h) << 16); }

#define MFMA(a,b,c) __builtin_amdgcn_mfma_f32_16x16x32_bf16((a),(b),(c),0,0,0)

#define LDP 72   // padded stride, used ONLY for the VALU-written W tile in attn

// swizzled element offset in a linear [rows][64] u16 tile: 16B granule g XOR (row&7)
DEV int SW(int row, int g){ return row*64 + (((g) ^ (row & 7)) << 3); }

// stage rows [r0, r0+8) of a [*][64] u16 tile; g0 = global ptr at (row r0, col 0),
// rs = global row stride (elements). LDS stays linear; source address pre-swizzled.
DEV void stage8(const u16* __restrict__ g0, int rs, u16* tile, int r0){
  int lane = threadIdx.x & 63;
  int r = lane >> 3, gl = (lane & 7) ^ (r & 7);
  const u16* src = g0 + (size_t)r * rs + gl * 8;
#if HAS_GLL
  __builtin_amdgcn_global_load_lds((const void*)src, (void*)(tile + r0*64), 16, 0, 0);
#else
  *(short8*)&tile[(r0 + r)*64 + (lane & 7)*8] = *(const short8*)src;
#endif
}

// ---------------- prep: fp32 -> bf16 hi (+ optional lo residual), 4 jobs fused ----------------
struct CvtJob { const float* src; u16* hi; u16* lo; };

__global__ void k_convert4(CvtJob j0, CvtJob j1, CvtJob j2, CvtJob j3, int n4){
  CvtJob j = (blockIdx.y==0) ? j0 : (blockIdx.y==1) ? j1 : (blockIdx.y==2) ? j2 : j3;
  int i = blockIdx.x * blockDim.x + threadIdx.x;
  int st = gridDim.x * blockDim.x;
  for (; i < n4; i += st){
    float4 v = ((const float4*)j.src)[i];
    u16 h0=f2bf(v.x), h1=f2bf(v.y), h2=f2bf(v.z), h3=f2bf(v.w);
    ushort4 o; o.x=h0; o.y=h1; o.z=h2; o.w=h3;
    ((ushort4*)j.hi)[i] = o;
    if (j.lo){
      ushort4 p;
      p.x=f2bf(v.x-bf2f(h0)); p.y=f2bf(v.y-bf2f(h1));
      p.z=f2bf(v.z-bf2f(h2)); p.w=f2bf(v.w-bf2f(h3));
      ((ushort4*)j.lo)[i] = p;
    }
  }
}

// ---------------- RoPE cos/sin table: cs[0:65536]=cos, cs[65536:]=sin ----------------
__global__ void k_cossin(float* __restrict__ cs){
  int t = blockIdx.x * blockDim.x + threadIdx.x;
  if (t >= 2048*32) return;
  int s = t >> 5, i = t & 31;
  float f = powf(10000.0f, -(float)i * (1.0f/32.0f));
  float ang = (float)s * f;
  cs[t]         = cosf(ang);
  cs[65536 + t] = sinf(ang);
}

// ---------------- fused projection (+RoPE+scale, or +transpose for V) ----------------
// MODE 0: q = rope(x@Wq^T + b) * 0.125 -> out [B,H,S,D] bf16   (3-term split GEMM)
// MODE 1: k = rope(x@Wk^T + b)         -> out [B,H,S,D] bf16   (3-term split GEMM)
// MODE 2: v = x@Wv^T + b               -> out = vT [B,H,D,S]   (plain GEMM)
template<int MODE>
__global__ __launch_bounds__(256, 2) void k_proj(
    const u16* __restrict__ Ah_g, const u16* __restrict__ Al_g,
    const u16* __restrict__ Wh_g, const u16* __restrict__ Wl_g,
    const float* __restrict__ bias, const float* __restrict__ cs,
    u16* __restrict__ out)
{
  __shared__ __align__(16) u16 smem[4*128*64];   // 64 KB
  u16* AhL = smem;
  u16* AlL = smem + 128*64;
  u16* BhL = smem + 2*128*64;
  u16* BlL = smem + 3*128*64;

  const int n0 = blockIdx.x * 128, m0 = blockIdx.y * 128;
  const int tid = threadIdx.x, lane = tid & 63, wv = tid >> 6;
  const int wm = wv >> 1, wn = wv & 1;
  const int l15 = lane & 15, l4 = lane >> 4;

  const f32x4 z4 = {0.f,0.f,0.f,0.f};
  f32x4 acc[4][4];
#pragma unroll
  for (int i=0;i<4;++i)
#pragma unroll
    for (int j=0;j<4;++j) acc[i][j] = z4;

  for (int kt = 0; kt < 16; ++kt){
    const int K0 = kt * 64;
#pragma unroll
    for (int t = 0; t < 4; ++t){
      int r0 = (wv*4 + t)*8;
      stage8(&Ah_g[(size_t)(m0+r0)*1024 + K0], 1024, AhL, r0);
      stage8(&Wh_g[(size_t)(n0+r0)*1024 + K0], 1024, BhL, r0);
      if (MODE != 2){
        stage8(&Al_g[(size_t)(m0+r0)*1024 + K0], 1024, AlL, r0);
        stage8(&Wl_g[(size_t)(n0+r0)*1024 + K0], 1024, BlL, r0);
      }
    }
    __syncthreads();
#pragma unroll
    for (int ks = 0; ks < 2; ++ks){
      const int ksg = l4 + ks*4;
      short8 ah[4], bh[4], al[4], bl[4];
#pragma unroll
      for (int mi=0;mi<4;++mi) ah[mi] = *(const short8*)&AhL[SW(wm*64+mi*16+l15, ksg)];
#pragma unroll
      for (int nf=0;nf<4;++nf) bh[nf] = *(const short8*)&BhL[SW(wn*64+nf*16+l15, ksg)];
      if (MODE != 2){
#pragma unroll
        for (int mi=0;mi<4;++mi) al[mi] = *(const short8*)&AlL[SW(wm*64+mi*16+l15, ksg)];
#pragma unroll
        for (int nf=0;nf<4;++nf) bl[nf] = *(const short8*)&BlL[SW(wn*64+nf*16+l15, ksg)];
      }
#pragma unroll
      for (int mi=0;mi<4;++mi)
#pragma unroll
        for (int nf=0;nf<4;++nf){
          acc[mi][nf] = MFMA(ah[mi], bh[nf], acc[mi][nf]);
          if (MODE != 2){
            acc[mi][nf] = MFMA(al[mi], bh[nf], acc[mi][nf]);
            acc[mi][nf] = MFMA(ah[mi], bl[nf], acc[mi][nf]);
          }
        }
    }
    __syncthreads();
  }

  if (MODE != 2){
    const int h = (n0 + wn*64) >> 6;   // wave covers exactly one head
    float bv[4];
#pragma unroll
    for (int nf=0;nf<4;++nf) bv[nf] = bias[n0 + wn*64 + nf*16 + l15];
#pragma unroll
    for (int mi=0;mi<4;++mi)
#pragma unroll
      for (int r=0;r<4;++r){
        int srow = m0 + wm*64 + mi*16 + l4*4 + r;
        int b = srow >> 11, s = srow & 2047;
#pragma unroll
        for (int half=0; half<2; ++half){
          int dmod = half*16 + l15;                       // d (<32); partner d+32
          float ct = cs[s*32 + dmod], st = cs[65536 + s*32 + dmod];
          float vlo = acc[mi][half  ][r] + bv[half  ];
          float vhi = acc[mi][half+2][r] + bv[half+2];
          float olo = vlo*ct - vhi*st;                    // d<32
          float ohi = vhi*ct + vlo*st;                    // d>=32
          if (MODE == 0){ olo *= 0.125f; ohi *= 0.125f; } // bake 1/sqrt(D) into q
          size_t base = ((size_t)(b*16 + h)*2048 + s)*64;
          out[base + dmod]      = f2bf(olo);
          out[base + dmod + 32] = f2bf(ohi);
        }
      }
  } else {
    // V: bias add, then LDS transpose -> vT [B,H,D,S]
    u16* T = smem;   // [128][132]; safe: loop ended with __syncthreads()
#pragma unroll
    for (int mi=0;mi<4;++mi)
#pragma unroll
      for (int nf=0;nf<4;++nf)
#pragma unroll
        for (int r=0;r<4;++r){
          int rowl = wm*64 + mi*16 + l4*4 + r;
          int coll = wn*64 + nf*16 + l15;
          T[rowl*132 + coll] = f2bf(acc[mi][nf][r] + bias[n0 + coll]);
        }
    __syncthreads();
    int col = tid >> 1, sh = tid & 1;
    int h = (n0 + col) >> 6, d = (n0 + col) & 63;
    int b = m0 >> 11;
    size_t gbase = ((size_t)(b*16 + h)*64 + d)*2048 + (m0 & 2047) + sh*64;
#pragma unroll
    for (int j=0;j<64;j+=8){
      short8 pk;
#pragma unroll
      for (int e=0;e<8;++e) pk[e] = (short)T[(sh*64 + j + e)*132 + col];
      *(short8*)&out[gbase + j] = pk;
    }
  }
}

// ---------------- attention: two-pass, 1-term QK (identical z both passes) ----------------
__global__ __launch_bounds__(256, 2) void k_attn(
    const u16* __restrict__ qh, const u16* __restrict__ kh,
    const u16* __restrict__ vt,
    float* __restrict__ wout,  // d_out attn weights [B,H,S,S] (FP32)
    u16* __restrict__ aout)    // attn output [B,S,H,D] (bf16, internal)
{
  __shared__ __align__(16) u16 KhL[64*64], VtL[64*64], WL[128*LDP];
  __shared__ float lpart[2][128];
  __shared__ float invl[128];

  const int m0 = blockIdx.x * 128;
  const int h = blockIdx.y, b = blockIdx.z;
  const size_t bh = (size_t)(b*16 + h);
  const u16* qh_p = qh + bh*2048*64;
  const u16* kh_p = kh + bh*2048*64;
  const u16* vt_p = vt + bh*64*2048;

  const int tid = threadIdx.x, lane = tid & 63, wv = tid >> 6;
  const int wm = wv >> 1, wn = wv & 1;
  const int l15 = lane & 15, l4 = lane >> 4;
  const f32x4 z4 = {0.f,0.f,0.f,0.f};

  // Q fragments resident in registers (q pre-scaled by 1/8, RoPE applied)
  short8 qhf[4][2];
#pragma unroll
  for (int mi=0;mi<4;++mi)
#pragma unroll
    for (int ks=0;ks<2;++ks)
      qhf[mi][ks] = *(const short8*)&qh_p[(size_t)(m0 + wm*64 + mi*16 + l15)*64 + l4*8 + ks*32];

  float lsum[4][4];
#pragma unroll
  for (int mi=0;mi<4;++mi)
#pragma unroll
    for (int r=0;r<4;++r) lsum[mi][r] = 0.f;

  // ---- pass 1: row sums of exp(z) ----
  for (int jt = 0; jt < 32; ++jt){
    const int j0 = jt*64;
#pragma unroll
    for (int t=0;t<2;++t){
      int r0 = (wv + t*4)*8;
      stage8(&kh_p[(size_t)(j0+r0)*64], 64, KhL, r0);
    }
    __syncthreads();
    f32x4 zf[4][2];
#pragma unroll
    for (int mi=0;mi<4;++mi){ zf[mi][0]=z4; zf[mi][1]=z4; }
#pragma unroll
    for (int ks=0;ks<2;++ks){
      const int ksg = l4 + ks*4;
      short8 kb0 = *(const short8*)&KhL[SW(wn*32      + l15, ksg)];
      short8 kb1 = *(const short8*)&KhL[SW(wn*32 + 16 + l15, ksg)];
#pragma unroll
      for (int mi=0;mi<4;++mi){
        zf[mi][0] = MFMA(qhf[mi][ks], kb0, zf[mi][0]);
        zf[mi][1] = MFMA(qhf[mi][ks], kb1, zf[mi][1]);
      }
    }
#pragma unroll
    for (int mi=0;mi<4;++mi)
#pragma unroll
      for (int r=0;r<4;++r){
        float p = __expf(fminf(zf[mi][0][r], 60.f)) + __expf(fminf(zf[mi][1][r], 60.f));
        p += __shfl_xor(p, 1, 64);
        p += __shfl_xor(p, 2, 64);
        p += __shfl_xor(p, 4, 64);
        p += __shfl_xor(p, 8, 64);
        lsum[mi][r] += p;
      }
    __syncthreads();
  }
  if (l15 == 0){
#pragma unroll
    for (int mi=0;mi<4;++mi)
#pragma unroll
      for (int r=0;r<4;++r)
        lpart[wn][wm*64 + mi*16 + l4*4 + r] = lsum[mi][r];
  }
  __syncthreads();
  if (tid < 128) invl[tid] = 1.0f / (lpart[0][tid] + lpart[1][tid]);
  __syncthreads();

  // ---- pass 2: same z, write w (fp32 direct), accumulate PV ----
  f32x4 oacc[4][2];
#pragma unroll
  for (int mi=0;mi<4;++mi){ oacc[mi][0]=z4; oacc[mi][1]=z4; }

  for (int jt = 0; jt < 32; ++jt){
    const int j0 = jt*64;
#pragma unroll
    for (int t=0;t<2;++t){
      int r0 = (wv + t*4)*8;
      stage8(&kh_p[(size_t)(j0+r0)*64], 64, KhL, r0);
      stage8(&vt_p[(size_t)r0*2048 + j0], 2048, VtL, r0);
    }
    __syncthreads();
    f32x4 zf[4][2];
#pragma unroll
    for (int mi=0;mi<4;++mi){ zf[mi][0]=z4; zf[mi][1]=z4; }
#pragma unroll
    for (int ks=0;ks<2;++ks){
      const int ksg = l4 + ks*4;
      short8 kb0 = *(const short8*)&KhL[SW(wn*32      + l15, ksg)];
      short8 kb1 = *(const short8*)&KhL[SW(wn*32 + 16 + l15, ksg)];
#pragma unroll
      for (int mi=0;mi<4;++mi){
        zf[mi][0] = MFMA(qhf[mi][ks], kb0, zf[mi][0]);
        zf[mi][1] = MFMA(qhf[mi][ks], kb1, zf[mi][1]);
      }
    }
#pragma unroll
    for (int mi=0;mi<4;++mi)
#pragma unroll
      for (int r=0;r<4;++r){
        int rowl = wm*64 + mi*16 + l4*4 + r;
        float il = invl[rowl];
        size_t gr = (bh*2048 + (size_t)(m0 + rowl))*2048 + j0;
#pragma unroll
        for (int nf=0;nf<2;++nf){
          float w = __expf(fminf(zf[mi][nf][r], 60.f)) * il;
          WL[rowl*LDP + wn*32 + nf*16 + l15] = f2bf(w);   // bf16 copy for PV
          wout[gr + wn*32 + nf*16 + l15] = w;             // fp32 to d_out
        }
      }
    __syncthreads();
#pragma unroll
    for (int ks=0;ks<2;++ks){   // PV: O += w * V
      const int ko = l4*8 + ks*32;
      const int ksg = l4 + ks*4;
      short8 aw[4], bvv[2];
#pragma unroll
      for (int mi=0;mi<4;++mi) aw[mi] = *(const short8*)&WL[(wm*64 + mi*16 + l15)*LDP + ko];
#pragma unroll
      for (int nf=0;nf<2;++nf) bvv[nf] = *(const short8*)&VtL[SW(wn*32 + nf*16 + l15, ksg)];
#pragma unroll
      for (int mi=0;mi<4;++mi)
#pragma unroll
        for (int nf=0;nf<2;++nf)
          oacc[mi][nf] = MFMA(aw[mi], bvv[nf], oacc[mi][nf]);
    }
    __syncthreads();
  }

#pragma unroll
  for (int mi=0;mi<4;++mi)
#pragma unroll
    for (int nf=0;nf<2;++nf)
#pragma unroll
      for (int r=0;r<4;++r){
        int rowl = wm*64 + mi*16 + l4*4 + r;
        int d = wn*32 + nf*16 + l15;
        aout[((size_t)(b*2048 + m0 + rowl)*16 + h)*64 + d] = f2bf(oacc[mi][nf][r]);
      }
}

// ---------------- output projection: out0 = attn_out @ Wo^T + bo ----------------
__global__ __launch_bounds__(256, 2) void k_oproj(
    const u16* __restrict__ A_g, const u16* __restrict__ W_g,
    const float* __restrict__ bias, float* __restrict__ out0)
{
  __shared__ __align__(16) u16 AhL[128*64];
  __shared__ __align__(16) u16 BhL[128*64];
  const int n0 = blockIdx.x * 128, m0 = blockIdx.y * 128;
  const int tid = threadIdx.x, lane = tid & 63, wv = tid >> 6;
  const int wm = wv >> 1, wn = wv & 1, l15 = lane & 15, l4 = lane >> 4;
  const f32x4 z4 = {0.f,0.f,0.f,0.f};
  f32x4 acc[4][4];
#pragma unroll
  for (int i=0;i<4;++i)
#pragma unroll
    for (int j=0;j<4;++j) acc[i][j] = z4;

  for (int kt = 0; kt < 16; ++kt){
    const int K0 = kt * 64;
#pragma unroll
    for (int t = 0; t < 4; ++t){
      int r0 = (wv*4 + t)*8;
      stage8(&A_g[(size_t)(m0+r0)*1024 + K0], 1024, AhL, r0);
      stage8(&W_g[(size_t)(n0+r0)*1024 + K0], 1024, BhL, r0);
    }
    __syncthreads();
#pragma unroll
    for (int ks = 0; ks < 2; ++ks){
      const int ksg = l4 + ks*4;
      short8 ah[4], bhh[4];
#pragma unroll
      for (int mi=0;mi<4;++mi) ah[mi] = *(const short8*)&AhL[SW(wm*64+mi*16+l15, ksg)];
#pragma unroll
      for (int nf=0;nf<4;++nf) bhh[nf] = *(const short8*)&BhL[SW(wn*64+nf*16+l15, ksg)];
#pragma unroll
      for (int mi=0;mi<4;++mi)
#pragma unroll
        for (int nf=0;nf<4;++nf)
          acc[mi][nf] = MFMA(ah[mi], bhh[nf], acc[mi][nf]);
    }
    __syncthreads();
  }
#pragma unroll
  for (int mi=0;mi<4;++mi)
#pragma unroll
    for (int nf=0;nf<4;++nf)
#pragma unroll
      for (int r=0;r<4;++r){
        int rowl = wm*64 + mi*16 + l4*4 + r;
        int coll = wn*64 + nf*16 + l15;
        out0[(size_t)(m0+rowl)*1024 + n0 + coll] = acc[mi][nf][r] + bias[n0+coll];
      }
}

// ---------------- launcher ----------------
extern "C" void kernel_launch(void* const* d_in, const int* in_sizes, int n_in,
                              void* d_out, int out_size, void* d_ws, size_t ws_size,
                              hipStream_t stream) {
  const float* query = (const float*)d_in[0];
  const float* key   = (const float*)d_in[1];
  const float* value = (const float*)d_in[2];
  const float* Wq = (const float*)d_in[3]; const float* bq = (const float*)d_in[4];
  const float* Wk = (const float*)d_in[5]; const float* bk = (const float*)d_in[6];
  const float* Wv = (const float*)d_in[7]; const float* bv = (const float*)d_in[8];
  const float* Wo = (const float*)d_in[9]; const float* bo = (const float*)d_in[10];

  float* out0 = (float*)d_out;                     // output (B,S,E), fp32
  float* out1 = out0 + (size_t)4096*1024;          // attn_weights (B,H,S,S), fp32

  char* cur = (char*)d_ws;
  auto take = [&](size_t bytes)->void*{
    void* p = (void*)cur; cur += (bytes + 255) & ~(size_t)255; return p;
  };
  u16* query_hi = (u16*)take(8388608);
  u16* query_lo = (u16*)take(8388608);
  u16* key_hi   = (u16*)take(8388608);
  u16* key_lo   = (u16*)take(8388608);
  u16* value_hi = (u16*)take(8388608);
  u16* Wq_hi = (u16*)take(2097152); u16* Wq_lo = (u16*)take(2097152);
  u16* Wk_hi = (u16*)take(2097152); u16* Wk_lo = (u16*)take(2097152);
  u16* Wv_hi = (u16*)take(2097152);
  u16* Wo_hi = (u16*)take(2097152);
  u16* q_hi = (u16*)take(8388608);
  u16* k_hi = (u16*)take(8388608);
  u16* vT   = (u16*)take(8388608);
  u16* attn_o = (u16*)take(8388608);
  float* cs = (float*)take(524288);

  CvtJob a0{query, query_hi, query_lo};
  CvtJob a1{key,   key_hi,   key_lo};
  CvtJob a2{value, value_hi, nullptr};
  k_convert4<<<dim3(512,3), 256, 0, stream>>>(a0, a1, a2, a0, 1048576);

  CvtJob w0{Wq, Wq_hi, Wq_lo};
  CvtJob w1{Wk, Wk_hi, Wk_lo};
  CvtJob w2{Wv, Wv_hi, nullptr};
  CvtJob w3{Wo, Wo_hi, nullptr};
  k_convert4<<<dim3(256,4), 256, 0, stream>>>(w0, w1, w2, w3, 262144);

  k_cossin<<<256, 256, 0, stream>>>(cs);

  k_proj<0><<<dim3(8,32), 256, 0, stream>>>(query_hi, query_lo, Wq_hi, Wq_lo, bq, cs, q_hi);
  k_proj<1><<<dim3(8,32), 256, 0, stream>>>(key_hi,   key_lo,   Wk_hi, Wk_lo, bk, cs, k_hi);
  k_proj<2><<<dim3(8,32), 256, 0, stream>>>(value_hi, nullptr,  Wv_hi, nullptr, bv, nullptr, vT);

  k_attn<<<dim3(16,16,2), 256, 0, stream>>>(q_hi, k_hi, vT, out1, attn_o);

  k_oproj<<<dim3(8,32), 256, 0, stream>>>(attn_o, Wo_hi, bo, out0);
}

// Round 5
// 324.389 us; speedup vs baseline: 1.3202x; 1.1579x over previous
//
#include <hip/hip_runtime.h>
#include <hip/hip_bf16.h>

// RotaryMultiheadAttention: B=2,S=2048,E=1024,H=16,D=64
// d_out FP32: [output (B,S,E)] ++ [attn_weights (B,H,S,S)]
// Numerics: plain 1-term bf16 GEMMs everywhere (error model anchored on r2/r3:
// predicted absmax ~1.8e-3 vs threshold 3.79e-3). fp32 RoPE epilogue;
// pass1/pass2 z bit-identical -> consistent softmax.
// Schedule: dbuf LDS + global_load_lds(16B) prefetch + raw s_barrier with
// counted s_waitcnt (lgkmcnt-only mid-iter; vmcnt(8) end-iter in attn pass2).
// NOTE: no LDS-pointer aggregates (hipcc addrspacecast static-init bug).

#define DEV static __device__ __forceinline__

typedef __attribute__((ext_vector_type(8))) short short8;
typedef __attribute__((ext_vector_type(4))) short sh4;
typedef __attribute__((ext_vector_type(4))) float f32x4;
typedef unsigned short u16;

#if defined(__has_builtin)
# if __has_builtin(__builtin_amdgcn_global_load_lds)
#  define HAS_GLL 1
# endif
#endif
#ifndef HAS_GLL
# define HAS_GLL 0
#endif

DEV u16 f2bf(float x){
  unsigned u = __float_as_uint(x);
  u += 0x7fff + ((u >> 16) & 1);           // RNE
  return (u16)(u >> 16);
}
DEV float bf2f(u16 h){ return __uint_as_float(((unsigned)h) << 16); }

#define MFMA(a,b,c) __builtin_amdgcn_mfma_f32_16x16x32_bf16((a),(b),(c),0,0,0)

#define LDP 72   // padded stride for the VALU-written W tile in attn
#define TILE (128*64)
#define KTILE (64*64)
#define VMCNT0   asm volatile("s_waitcnt vmcnt(0)" ::: "memory")
#define VMCNT8   asm volatile("s_waitcnt vmcnt(8)" ::: "memory")
#define LGKM0    asm volatile("s_waitcnt lgkmcnt(0)" ::: "memory")
#define SBAR     __builtin_amdgcn_s_barrier()

// swizzled element offset in a linear [rows][64] u16 tile: 16B granule g XOR (row&7)
DEV int SW(int row, int g){ return row*64 + (((g) ^ (row & 7)) << 3); }

// stage rows [r0, r0+8) of a [*][64] u16 tile; g0 = global ptr at (row r0, col 0),
// rs = global row stride (elems). LDS linear; source pre-swizzled (m173 pattern).
DEV void stage8(const u16* __restrict__ g0, int rs, u16* tile, int r0){
  int lane = threadIdx.x & 63;
  int r = lane >> 3, gl = (lane & 7) ^ (r & 7);
  const u16* src = g0 + (size_t)r * rs + gl * 8;
#if HAS_GLL
  __builtin_amdgcn_global_load_lds((const void*)src, (void*)(tile + r0*64), 16, 0, 0);
#else
  *(short8*)&tile[(r0 + r)*64 + (lane & 7)*8] = *(const short8*)src;
#endif
}

// ---------------- fused prep: 7 fp32->bf16 converts + cos/sin table ----------------
struct PrepArgs { const float* src[7]; u16* dst[7]; int n4[7]; float* cs; };

__global__ void k_prep(PrepArgs a){
  int y = blockIdx.y;
  int t0 = blockIdx.x * blockDim.x + threadIdx.x;
  if (y == 7){
    if (t0 < 65536){
      int s = t0 >> 5, i = t0 & 31;
      float f = powf(10000.0f, -(float)i * (1.0f/32.0f));
      float ang = (float)s * f;
      a.cs[t0]         = cosf(ang);
      a.cs[65536 + t0] = sinf(ang);
    }
    return;
  }
  const float* src = a.src[y]; u16* dst = a.dst[y]; int n4 = a.n4[y];
  int st = gridDim.x * blockDim.x;
  for (int i = t0; i < n4; i += st){
    float4 v = ((const float4*)src)[i];
    ushort4 o; o.x=f2bf(v.x); o.y=f2bf(v.y); o.z=f2bf(v.z); o.w=f2bf(v.w);
    ((ushort4*)dst)[i] = o;
  }
}

// ---------------- fused projection (+RoPE+scale, or +transpose for V) ----------------
// MODE 0: q = rope(x@Wq^T + b) * 0.125 -> out [B,H,S,D] bf16
// MODE 1: k = rope(x@Wk^T + b)         -> out [B,H,S,D] bf16
// MODE 2: v = x@Wv^T + b               -> out = vT [B,H,D,S]
template<int MODE>
__global__ __launch_bounds__(256, 2) void k_proj(
    const u16* __restrict__ A_g, const u16* __restrict__ W_g,
    const float* __restrict__ bias, const float* __restrict__ cs,
    u16* __restrict__ out)
{
  __shared__ __align__(16) u16 smem[4*TILE];   // 64 KB: A0 A1 B0 B1

  const int n0 = blockIdx.x * 128, m0 = blockIdx.y * 128;
  const int tid = threadIdx.x, lane = tid & 63, wv = tid >> 6;
  const int wm = wv >> 1, wn = wv & 1;
  const int l15 = lane & 15, l4 = lane >> 4;

  const f32x4 z4 = {0.f,0.f,0.f,0.f};
  f32x4 acc[4][4];
#pragma unroll
  for (int i=0;i<4;++i)
#pragma unroll
    for (int j=0;j<4;++j) acc[i][j] = z4;

  auto stageAB = [&](int kt, int buf){
    u16* Ab = smem + buf*TILE;
    u16* Bb = smem + (2+buf)*TILE;
#pragma unroll
    for (int t = 0; t < 4; ++t){
      int r0 = (wv*4 + t)*8;
      stage8(&A_g[(size_t)(m0+r0)*1024 + kt*64], 1024, Ab, r0);
      stage8(&W_g[(size_t)(n0+r0)*1024 + kt*64], 1024, Bb, r0);
    }
  };

  stageAB(0, 0);
  VMCNT0; SBAR;

  for (int kt = 0; kt < 16; ++kt){
    const int cur = kt & 1;
    if (kt < 15) stageAB(kt+1, cur^1);
    const u16* Ac = smem + cur*TILE;
    const u16* Bc = smem + (2+cur)*TILE;
#pragma unroll
    for (int ks = 0; ks < 2; ++ks){
      const int ksg = l4 + ks*4;
      short8 ah[4], bh[4];
#pragma unroll
      for (int mi=0;mi<4;++mi) ah[mi] = *(const short8*)&Ac[SW(wm*64+mi*16+l15, ksg)];
#pragma unroll
      for (int nf=0;nf<4;++nf) bh[nf] = *(const short8*)&Bc[SW(wn*64+nf*16+l15, ksg)];
#pragma unroll
      for (int mi=0;mi<4;++mi)
#pragma unroll
        for (int nf=0;nf<4;++nf)
          acc[mi][nf] = MFMA(ah[mi], bh[nf], acc[mi][nf]);
    }
    VMCNT0; SBAR;
  }

  if (MODE != 2){
    const int h = (n0 + wn*64) >> 6;   // wave covers exactly one head
    float bv[4];
#pragma unroll
    for (int nf=0;nf<4;++nf) bv[nf] = bias[n0 + wn*64 + nf*16 + l15];
#pragma unroll
    for (int mi=0;mi<4;++mi)
#pragma unroll
      for (int r=0;r<4;++r){
        int srow = m0 + wm*64 + mi*16 + l4*4 + r;
        int b = srow >> 11, s = srow & 2047;
#pragma unroll
        for (int half=0; half<2; ++half){
          int dmod = half*16 + l15;                       // d (<32); partner d+32
          float ct = cs[s*32 + dmod], st = cs[65536 + s*32 + dmod];
          float vlo = acc[mi][half  ][r] + bv[half  ];
          float vhi = acc[mi][half+2][r] + bv[half+2];
          float olo = vlo*ct - vhi*st;                    // d<32
          float ohi = vhi*ct + vlo*st;                    // d>=32
          if (MODE == 0){ olo *= 0.125f; ohi *= 0.125f; } // bake 1/sqrt(D) into q
          size_t base = ((size_t)(b*16 + h)*2048 + s)*64;
          out[base + dmod]      = f2bf(olo);
          out[base + dmod + 32] = f2bf(ohi);
        }
      }
  } else {
    // V: bias add, LDS transpose -> vT [B,H,D,S]
    u16* T = smem;               // reuse full 64KB; stride 130 (33274B < 64KB)
    const int TST = 130;
#pragma unroll
    for (int mi=0;mi<4;++mi)
#pragma unroll
      for (int nf=0;nf<4;++nf)
#pragma unroll
        for (int r=0;r<4;++r){
          int rowl = wm*64 + mi*16 + l4*4 + r;
          int coll = wn*64 + nf*16 + l15;
          T[rowl*TST + coll] = f2bf(acc[mi][nf][r] + bias[n0 + coll]);
        }
    __syncthreads();
    int col = tid >> 1, sh = tid & 1;
    int h = (n0 + col) >> 6, d = (n0 + col) & 63;
    int b = m0 >> 11;
    size_t gbase = ((size_t)(b*16 + h)*64 + d)*2048 + (m0 & 2047) + sh*64;
#pragma unroll
    for (int j=0;j<64;j+=8){
      short8 pk;
#pragma unroll
      for (int e=0;e<8;++e) pk[e] = (short)T[(sh*64 + j + e)*TST + col];
      *(short8*)&out[gbase + j] = pk;
    }
  }
}

// ---------------- attention: two-pass, 1-term QK (identical z both passes) ----------------
__global__ __launch_bounds__(256, 2) void k_attn(
    const u16* __restrict__ qh, const u16* __restrict__ kh,
    const u16* __restrict__ vt,
    float* __restrict__ wout,  // d_out attn weights [B,H,S,S] (FP32)
    u16* __restrict__ aout)    // attn output [B,S,H,D] (bf16, internal)
{
  __shared__ __align__(16) u16 KVs[4*KTILE];   // Kh0 Kh1 Vt0 Vt1
  __shared__ __align__(16) u16 WL[128*LDP];
  __shared__ float lpart[2][128];
  __shared__ float invl[128];

  // XCD-aware flat-grid swizzle: all 16 Q-blocks of one (b,h) on one XCD
  const int id = blockIdx.x;                 // 0..511
  const int xcd = id & 7, s5 = id >> 3;      // 64 slots per xcd
  const int pair = xcd*4 + (s5 >> 4);        // (b,h) pair 0..31
  const int m0 = (s5 & 15) * 128;
  const int h = pair & 15, b = pair >> 4;

  const size_t bh = (size_t)(b*16 + h);
  const u16* qh_p = qh + bh*2048*64;
  const u16* kh_p = kh + bh*2048*64;
  const u16* vt_p = vt + bh*64*2048;

  const int tid = threadIdx.x, lane = tid & 63, wv = tid >> 6;
  const int wm = wv >> 1, wn = wv & 1;
  const int l15 = lane & 15, l4 = lane >> 4;
  const f32x4 z4 = {0.f,0.f,0.f,0.f};

  auto stageK = [&](int jt, int buf){
    u16* Kb = KVs + buf*KTILE;
#pragma unroll
    for (int t=0;t<2;++t){
      int r0 = (wv + t*4)*8;
      stage8(&kh_p[(size_t)(jt*64 + r0)*64], 64, Kb, r0);
    }
  };
  auto stageV = [&](int jt, int buf){
    u16* Vb = KVs + (2+buf)*KTILE;
#pragma unroll
    for (int t=0;t<2;++t){
      int r0 = (wv + t*4)*8;
      stage8(&vt_p[(size_t)r0*2048 + jt*64], 2048, Vb, r0);
    }
  };

  // Q fragments resident in registers (q pre-scaled by 1/8, RoPE applied)
  short8 qhf[4][2];
#pragma unroll
  for (int mi=0;mi<4;++mi)
#pragma unroll
    for (int ks=0;ks<2;++ks)
      qhf[mi][ks] = *(const short8*)&qh_p[(size_t)(m0 + wm*64 + mi*16 + l15)*64 + l4*8 + ks*32];

  float lsum[4][4];
#pragma unroll
  for (int mi=0;mi<4;++mi)
#pragma unroll
    for (int r=0;r<4;++r) lsum[mi][r] = 0.f;

  // ---- pass 1: row sums of exp(z), 2-phase prefetch ----
  stageK(0, 0);
  VMCNT0; SBAR;
  for (int jt = 0; jt < 32; ++jt){
    const int cur = jt & 1;
    if (jt < 31) stageK(jt+1, cur^1);
    const u16* Kc = KVs + cur*KTILE;
    f32x4 zf[4][2];
#pragma unroll
    for (int mi=0;mi<4;++mi){ zf[mi][0]=z4; zf[mi][1]=z4; }
#pragma unroll
    for (int ks=0;ks<2;++ks){
      const int ksg = l4 + ks*4;
      short8 kb0 = *(const short8*)&Kc[SW(wn*32      + l15, ksg)];
      short8 kb1 = *(const short8*)&Kc[SW(wn*32 + 16 + l15, ksg)];
#pragma unroll
      for (int mi=0;mi<4;++mi){
        zf[mi][0] = MFMA(qhf[mi][ks], kb0, zf[mi][0]);
        zf[mi][1] = MFMA(qhf[mi][ks], kb1, zf[mi][1]);
      }
    }
#pragma unroll
    for (int mi=0;mi<4;++mi)
#pragma unroll
      for (int r=0;r<4;++r){
        float p = __expf(fminf(zf[mi][0][r], 60.f)) + __expf(fminf(zf[mi][1][r], 60.f));
        p += __shfl_xor(p, 1, 64);
        p += __shfl_xor(p, 2, 64);
        p += __shfl_xor(p, 4, 64);
        p += __shfl_xor(p, 8, 64);
        lsum[mi][r] += p;
      }
    VMCNT0; SBAR;
  }

  if (l15 == 0){
#pragma unroll
    for (int mi=0;mi<4;++mi)
#pragma unroll
      for (int r=0;r<4;++r)
        lpart[wn][wm*64 + mi*16 + l4*4 + r] = lsum[mi][r];
  }
  __syncthreads();
  if (tid < 128) invl[tid] = 1.0f / (lpart[0][tid] + lpart[1][tid]);
  __syncthreads();

  // ---- pass 2: same z, w -> WL(bf16) -> wout(fp32 coalesced), PV ----
  f32x4 oacc[4][2];
#pragma unroll
  for (int mi=0;mi<4;++mi){ oacc[mi][0]=z4; oacc[mi][1]=z4; }

  stageK(0, 0); stageV(0, 0);
  VMCNT0; SBAR;
  for (int jt = 0; jt < 32; ++jt){
    const int cur = jt & 1;
    if (jt < 31){ stageK(jt+1, cur^1); stageV(jt+1, cur^1); }   // 4 gll / wave
    const u16* Kc = KVs + cur*KTILE;
    const u16* Vc = KVs + (2+cur)*KTILE;
    f32x4 zf[4][2];
#pragma unroll
    for (int mi=0;mi<4;++mi){ zf[mi][0]=z4; zf[mi][1]=z4; }
#pragma unroll
    for (int ks=0;ks<2;++ks){
      const int ksg = l4 + ks*4;
      short8 kb0 = *(const short8*)&Kc[SW(wn*32      + l15, ksg)];
      short8 kb1 = *(const short8*)&Kc[SW(wn*32 + 16 + l15, ksg)];
#pragma unroll
      for (int mi=0;mi<4;++mi){
        zf[mi][0] = MFMA(qhf[mi][ks], kb0, zf[mi][0]);
        zf[mi][1] = MFMA(qhf[mi][ks], kb1, zf[mi][1]);
      }
    }
#pragma unroll
    for (int mi=0;mi<4;++mi)
#pragma unroll
      for (int r=0;r<4;++r){
        int rowl = wm*64 + mi*16 + l4*4 + r;
        float il = invl[rowl];
#pragma unroll
        for (int nf=0;nf<2;++nf){
          float w = __expf(fminf(zf[mi][nf][r], 60.f)) * il;
          WL[rowl*LDP + wn*32 + nf*16 + l15] = f2bf(w);
        }
      }
    LGKM0; SBAR;                   // WL visible; do NOT drain vmem (stores in flight)
    {  // coalesced fp32 weight write from WL
      int row = tid >> 4, c4 = (tid & 15) * 4;
      size_t gb = (bh*2048 + (size_t)m0)*2048 + jt*64 + c4;
#pragma unroll
      for (int i=0;i<8;++i){
        int rr = row + i*16;
        sh4 v = *(const sh4*)&WL[rr*LDP + c4];
        float4 o; o.x=bf2f((u16)v[0]); o.y=bf2f((u16)v[1]); o.z=bf2f((u16)v[2]); o.w=bf2f((u16)v[3]);
        *(float4*)&wout[gb + (size_t)rr*2048] = o;
      }
    }
#pragma unroll
    for (int ks=0;ks<2;++ks){   // PV: O += w * V
      const int ko = l4*8 + ks*32;
      const int ksg = l4 + ks*4;
      short8 aw[4], bvv[2];
#pragma unroll
      for (int mi=0;mi<4;++mi) aw[mi] = *(const short8*)&WL[(wm*64 + mi*16 + l15)*LDP + ko];
#pragma unroll
      for (int nf=0;nf<2;++nf) bvv[nf] = *(const short8*)&Vc[SW(wn*32 + nf*16 + l15, ksg)];
#pragma unroll
      for (int mi=0;mi<4;++mi)
#pragma unroll
        for (int nf=0;nf<2;++nf)
          oacc[mi][nf] = MFMA(aw[mi], bvv[nf], oacc[mi][nf]);
    }
    VMCNT8; SBAR;   // drains the 4 glls (oldest); leaves this iter's 8 stores in flight
  }

#pragma unroll
  for (int mi=0;mi<4;++mi)
#pragma unroll
    for (int nf=0;nf<2;++nf)
#pragma unroll
      for (int r=0;r<4;++r){
        int rowl = wm*64 + mi*16 + l4*4 + r;
        int d = wn*32 + nf*16 + l15;
        aout[((size_t)(b*2048 + m0 + rowl)*16 + h)*64 + d] = f2bf(oacc[mi][nf][r]);
      }
}

// ---------------- output projection: out0 = attn_out @ Wo^T + bo ----------------
__global__ __launch_bounds__(256, 2) void k_oproj(
    const u16* __restrict__ A_g, const u16* __restrict__ W_g,
    const float* __restrict__ bias, float* __restrict__ out0)
{
  __shared__ __align__(16) u16 smem[4*TILE];
  const int n0 = blockIdx.x * 128, m0 = blockIdx.y * 128;
  const int tid = threadIdx.x, lane = tid & 63, wv = tid >> 6;
  const int wm = wv >> 1, wn = wv & 1, l15 = lane & 15, l4 = lane >> 4;
  const f32x4 z4 = {0.f,0.f,0.f,0.f};
  f32x4 acc[4][4];
#pragma unroll
  for (int i=0;i<4;++i)
#pragma unroll
    for (int j=0;j<4;++j) acc[i][j] = z4;

  auto stageAB = [&](int kt, int buf){
    u16* Ab = smem + buf*TILE;
    u16* Bb = smem + (2+buf)*TILE;
#pragma unroll
    for (int t = 0; t < 4; ++t){
      int r0 = (wv*4 + t)*8;
      stage8(&A_g[(size_t)(m0+r0)*1024 + kt*64], 1024, Ab, r0);
      stage8(&W_g[(size_t)(n0+r0)*1024 + kt*64], 1024, Bb, r0);
    }
  };

  stageAB(0, 0);
  VMCNT0; SBAR;
  for (int kt = 0; kt < 16; ++kt){
    const int cur = kt & 1;
    if (kt < 15) stageAB(kt+1, cur^1);
    const u16* Ac = smem + cur*TILE;
    const u16* Bc = smem + (2+cur)*TILE;
#pragma unroll
    for (int ks = 0; ks < 2; ++ks){
      const int ksg = l4 + ks*4;
      short8 ah[4], bhh[4];
#pragma unroll
      for (int mi=0;mi<4;++mi) ah[mi] = *(const short8*)&Ac[SW(wm*64+mi*16+l15, ksg)];
#pragma unroll
      for (int nf=0;nf<4;++nf) bhh[nf] = *(const short8*)&Bc[SW(wn*64+nf*16+l15, ksg)];
#pragma unroll
      for (int mi=0;mi<4;++mi)
#pragma unroll
        for (int nf=0;nf<4;++nf)
          acc[mi][nf] = MFMA(ah[mi], bhh[nf], acc[mi][nf]);
    }
    VMCNT0; SBAR;
  }
#pragma unroll
  for (int mi=0;mi<4;++mi)
#pragma unroll
    for (int nf=0;nf<4;++nf)
#pragma unroll
      for (int r=0;r<4;++r){
        int rowl = wm*64 + mi*16 + l4*4 + r;
        int coll = wn*64 + nf*16 + l15;
        out0[(size_t)(m0+rowl)*1024 + n0 + coll] = acc[mi][nf][r] + bias[n0+coll];
      }
}

// ---------------- launcher ----------------
extern "C" void kernel_launch(void* const* d_in, const int* in_sizes, int n_in,
                              void* d_out, int out_size, void* d_ws, size_t ws_size,
                              hipStream_t stream) {
  const float* query = (const float*)d_in[0];
  const float* key   = (const float*)d_in[1];
  const float* value = (const float*)d_in[2];
  const float* Wq = (const float*)d_in[3]; const float* bq = (const float*)d_in[4];
  const float* Wk = (const float*)d_in[5]; const float* bk = (const float*)d_in[6];
  const float* Wv = (const float*)d_in[7]; const float* bv = (const float*)d_in[8];
  const float* Wo = (const float*)d_in[9]; const float* bo = (const float*)d_in[10];

  float* out0 = (float*)d_out;                     // output (B,S,E), fp32
  float* out1 = out0 + (size_t)4096*1024;          // attn_weights (B,H,S,S), fp32

  char* cur = (char*)d_ws;
  auto take = [&](size_t bytes)->void*{
    void* p = (void*)cur; cur += (bytes + 255) & ~(size_t)255; return p;
  };
  u16* query_hi = (u16*)take(8388608);
  u16* key_hi   = (u16*)take(8388608);
  u16* value_hi = (u16*)take(8388608);
  u16* Wq_hi = (u16*)take(2097152);
  u16* Wk_hi = (u16*)take(2097152);
  u16* Wv_hi = (u16*)take(2097152);
  u16* Wo_hi = (u16*)take(2097152);
  u16* q_hi = (u16*)take(8388608);
  u16* k_hi = (u16*)take(8388608);
  u16* vT   = (u16*)take(8388608);
  u16* attn_o = (u16*)take(8388608);
  float* cs = (float*)take(524288);

  PrepArgs pa;
  pa.src[0]=query; pa.dst[0]=query_hi; pa.n4[0]=1048576;
  pa.src[1]=key;   pa.dst[1]=key_hi;   pa.n4[1]=1048576;
  pa.src[2]=value; pa.dst[2]=value_hi; pa.n4[2]=1048576;
  pa.src[3]=Wq;    pa.dst[3]=Wq_hi;    pa.n4[3]=262144;
  pa.src[4]=Wk;    pa.dst[4]=Wk_hi;    pa.n4[4]=262144;
  pa.src[5]=Wv;    pa.dst[5]=Wv_hi;    pa.n4[5]=262144;
  pa.src[6]=Wo;    pa.dst[6]=Wo_hi;    pa.n4[6]=262144;
  pa.cs = cs;
  k_prep<<<dim3(512,8), 256, 0, stream>>>(pa);

  k_proj<0><<<dim3(8,32), 256, 0, stream>>>(query_hi, Wq_hi, bq, cs, q_hi);
  k_proj<1><<<dim3(8,32), 256, 0, stream>>>(key_hi,   Wk_hi, bk, cs, k_hi);
  k_proj<2><<<dim3(8,32), 256, 0, stream>>>(value_hi, Wv_hi, bv, nullptr, vT);

  k_attn<<<512, 256, 0, stream>>>(q_hi, k_hi, vT, out1, attn_o);

  k_oproj<<<dim3(8,32), 256, 0, stream>>>(attn_o, Wo_hi, bo, out0);
}

// Round 6
// 313.951 us; speedup vs baseline: 1.3641x; 1.0332x over previous
//
#include <hip/hip_runtime.h>
#include <hip/hip_bf16.h>

// RotaryMultiheadAttention: B=2,S=2048,E=1024,H=16,D=64
// d_out FP32: [output (B,S,E)] ++ [attn_weights (B,H,S,S)]
// r6: k_attn reads K/V frags DIRECT from global (L2-resident; no LDS staging,
// pass1 barrier-free, pass2 1 barrier/iter w/ dbuf WL); exp2 with log2e folded
// into q-scale; wout stored straight from registers; QKV projections fused.

#define DEV static __device__ __forceinline__

typedef __attribute__((ext_vector_type(8))) short short8;
typedef __attribute__((ext_vector_type(4))) float f32x4;
typedef unsigned short u16;

#if defined(__has_builtin)
# if __has_builtin(__builtin_amdgcn_global_load_lds)
#  define HAS_GLL 1
# endif
#endif
#ifndef HAS_GLL
# define HAS_GLL 0
#endif

DEV u16 f2bf(float x){
  unsigned u = __float_as_uint(x);
  u += 0x7fff + ((u >> 16) & 1);           // RNE
  return (u16)(u >> 16);
}
DEV float bf2f(u16 h){ return __uint_as_float(((unsigned)h) << 16); }

#define MFMA(a,b,c) __builtin_amdgcn_mfma_f32_16x16x32_bf16((a),(b),(c),0,0,0)

#define LDP 72          // padded stride for the WL tile (bf16)
#define TILE (128*64)
#define QSCALE 0.18033688f   // 0.125 * log2(e): z' = log2e * (q.k)/8 -> exp2
#define VMCNT0   asm volatile("s_waitcnt vmcnt(0)" ::: "memory")
#define LGKM0    asm volatile("s_waitcnt lgkmcnt(0)" ::: "memory")
#define SBAR     __builtin_amdgcn_s_barrier()

// swizzled element offset in a linear [rows][64] u16 tile: 16B granule g XOR (row&7)
DEV int SW(int row, int g){ return row*64 + (((g) ^ (row & 7)) << 3); }

// stage rows [r0, r0+8) of a [*][64] u16 tile (GEMM kernels only)
DEV void stage8(const u16* __restrict__ g0, int rs, u16* tile, int r0){
  int lane = threadIdx.x & 63;
  int r = lane >> 3, gl = (lane & 7) ^ (r & 7);
  const u16* src = g0 + (size_t)r * rs + gl * 8;
#if HAS_GLL
  __builtin_amdgcn_global_load_lds((const void*)src, (void*)(tile + r0*64), 16, 0, 0);
#else
  *(short8*)&tile[(r0 + r)*64 + (lane & 7)*8] = *(const short8*)src;
#endif
}

// ---------------- fused prep: 7 fp32->bf16 converts + cos/sin table ----------------
struct PrepArgs { const float* src[7]; u16* dst[7]; int n4[7]; float* cs; };

__global__ void k_prep(PrepArgs a){
  int y = blockIdx.y;
  int t0 = blockIdx.x * blockDim.x + threadIdx.x;
  if (y == 7){
    if (t0 < 65536){
      int s = t0 >> 5, i = t0 & 31;
      float f = powf(10000.0f, -(float)i * (1.0f/32.0f));
      float ang = (float)s * f;
      a.cs[t0]         = cosf(ang);
      a.cs[65536 + t0] = sinf(ang);
    }
    return;
  }
  const float* src = a.src[y]; u16* dst = a.dst[y]; int n4 = a.n4[y];
  int st = gridDim.x * blockDim.x;
  for (int i = t0; i < n4; i += st){
    float4 v = ((const float4*)src)[i];
    ushort4 o; o.x=f2bf(v.x); o.y=f2bf(v.y); o.z=f2bf(v.z); o.w=f2bf(v.w);
    ((ushort4*)dst)[i] = o;
  }
}

// ---------------- fused QKV projection ----------------
// sec 0: q = rope(x@Wq^T+b)*QSCALE -> [B,H,S,D];  sec 1: k = rope(..) -> [B,H,S,D]
// sec 2: v = x@Wv^T+b -> vT [B,H,D,S]
__global__ __launch_bounds__(256, 2) void k_projqkv(
    const u16* __restrict__ qA, const u16* __restrict__ kA, const u16* __restrict__ vA,
    const u16* __restrict__ Wqp, const u16* __restrict__ Wkp, const u16* __restrict__ Wvp,
    const float* __restrict__ bqp, const float* __restrict__ bkp, const float* __restrict__ bvp,
    const float* __restrict__ cs,
    u16* __restrict__ qO, u16* __restrict__ kO, u16* __restrict__ vO)
{
  __shared__ __align__(16) u16 smem[4*TILE];   // 64 KB: A0 A1 B0 B1

  const int sec = blockIdx.x >> 3;
  const u16* A_g = (sec==0) ? qA : (sec==1) ? kA : vA;
  const u16* W_g = (sec==0) ? Wqp : (sec==1) ? Wkp : Wvp;
  const float* bias = (sec==0) ? bqp : (sec==1) ? bkp : bvp;
  u16* out = (sec==0) ? qO : (sec==1) ? kO : vO;

  const int n0 = (blockIdx.x & 7) * 128, m0 = blockIdx.y * 128;
  const int tid = threadIdx.x, lane = tid & 63, wv = tid >> 6;
  const int wm = wv >> 1, wn = wv & 1;
  const int l15 = lane & 15, l4 = lane >> 4;

  const f32x4 z4 = {0.f,0.f,0.f,0.f};
  f32x4 acc[4][4];
#pragma unroll
  for (int i=0;i<4;++i)
#pragma unroll
    for (int j=0;j<4;++j) acc[i][j] = z4;

  auto stageAB = [&](int kt, int buf){
    u16* Ab = smem + buf*TILE;
    u16* Bb = smem + (2+buf)*TILE;
#pragma unroll
    for (int t = 0; t < 4; ++t){
      int r0 = (wv*4 + t)*8;
      stage8(&A_g[(size_t)(m0+r0)*1024 + kt*64], 1024, Ab, r0);
      stage8(&W_g[(size_t)(n0+r0)*1024 + kt*64], 1024, Bb, r0);
    }
  };

  stageAB(0, 0);
  VMCNT0; SBAR;

  for (int kt = 0; kt < 16; ++kt){
    const int cur = kt & 1;
    if (kt < 15) stageAB(kt+1, cur^1);
    const u16* Ac = smem + cur*TILE;
    const u16* Bc = smem + (2+cur)*TILE;
#pragma unroll
    for (int ks = 0; ks < 2; ++ks){
      const int ksg = l4 + ks*4;
      short8 ah[4], bh[4];
#pragma unroll
      for (int mi=0;mi<4;++mi) ah[mi] = *(const short8*)&Ac[SW(wm*64+mi*16+l15, ksg)];
#pragma unroll
      for (int nf=0;nf<4;++nf) bh[nf] = *(const short8*)&Bc[SW(wn*64+nf*16+l15, ksg)];
#pragma unroll
      for (int mi=0;mi<4;++mi)
#pragma unroll
        for (int nf=0;nf<4;++nf)
          acc[mi][nf] = MFMA(ah[mi], bh[nf], acc[mi][nf]);
    }
    VMCNT0; SBAR;
  }

  if (sec != 2){
    const int h = (n0 + wn*64) >> 6;   // wave covers exactly one head
    const float sc = (sec==0) ? QSCALE : 1.0f;
    float bv4[4];
#pragma unroll
    for (int nf=0;nf<4;++nf) bv4[nf] = bias[n0 + wn*64 + nf*16 + l15];
#pragma unroll
    for (int mi=0;mi<4;++mi)
#pragma unroll
      for (int r=0;r<4;++r){
        int srow = m0 + wm*64 + mi*16 + l4*4 + r;
        int b = srow >> 11, s = srow & 2047;
#pragma unroll
        for (int half=0; half<2; ++half){
          int dmod = half*16 + l15;                       // d (<32); partner d+32
          float ct = cs[s*32 + dmod], st = cs[65536 + s*32 + dmod];
          float vlo = acc[mi][half  ][r] + bv4[half  ];
          float vhi = acc[mi][half+2][r] + bv4[half+2];
          float olo = (vlo*ct - vhi*st) * sc;             // d<32
          float ohi = (vhi*ct + vlo*st) * sc;             // d>=32
          size_t base = ((size_t)(b*16 + h)*2048 + s)*64;
          out[base + dmod]      = f2bf(olo);
          out[base + dmod + 32] = f2bf(ohi);
        }
      }
  } else {
    // V: bias add, LDS transpose -> vT [B,H,D,S]
    u16* T = smem;
    const int TST = 130;
#pragma unroll
    for (int mi=0;mi<4;++mi)
#pragma unroll
      for (int nf=0;nf<4;++nf)
#pragma unroll
        for (int r=0;r<4;++r){
          int rowl = wm*64 + mi*16 + l4*4 + r;
          int coll = wn*64 + nf*16 + l15;
          T[rowl*TST + coll] = f2bf(acc[mi][nf][r] + bias[n0 + coll]);
        }
    __syncthreads();
    int col = tid >> 1, sh = tid & 1;
    int h = (n0 + col) >> 6, d = (n0 + col) & 63;
    int b = m0 >> 11;
    size_t gbase = ((size_t)(b*16 + h)*64 + d)*2048 + (m0 & 2047) + sh*64;
#pragma unroll
    for (int j=0;j<64;j+=8){
      short8 pk;
#pragma unroll
      for (int e=0;e<8;++e) pk[e] = (short)T[(sh*64 + j + e)*TST + col];
      *(short8*)&out[gbase + j] = pk;
    }
  }
}

// ---------------- attention: two-pass, K/V frags direct from global (L2) ----------------
__global__ __launch_bounds__(256, 2) void k_attn(
    const u16* __restrict__ qh, const u16* __restrict__ kh,
    const u16* __restrict__ vt,
    float* __restrict__ wout,  // d_out attn weights [B,H,S,S] (FP32)
    u16* __restrict__ aout)    // attn output [B,S,H,D] (bf16, internal)
{
  __shared__ __align__(16) u16 WL[2*128*LDP];   // dbuf PV A-operand tile
  __shared__ float lpart[2][128];
  __shared__ float invl[128];

  // XCD-aware flat-grid swizzle: all 16 Q-blocks of one (b,h) on one XCD
  const int id = blockIdx.x;                 // 0..511
  const int xcd = id & 7, s5 = id >> 3;
  const int pair = xcd*4 + (s5 >> 4);
  const int m0 = (s5 & 15) * 128;
  const int h = pair & 15, b = pair >> 4;

  const size_t bh = (size_t)(b*16 + h);
  const u16* qh_p = qh + bh*2048*64;
  const u16* kh_p = kh + bh*2048*64;
  const u16* vt_p = vt + bh*64*2048;

  const int tid = threadIdx.x, lane = tid & 63, wv = tid >> 6;
  const int wm = wv >> 1, wn = wv & 1;
  const int l15 = lane & 15, l4 = lane >> 4;
  const f32x4 z4 = {0.f,0.f,0.f,0.f};

  // K-frag loader: 4 x 16B direct loads (rows j = jt*64 + wn*32 + {l15, l15+16})
  auto loadK = [&](short8* KB, int jt){
    const u16* kp = kh_p + ((size_t)(jt*64 + wn*32 + l15))*64 + l4*8;
    KB[0] = *(const short8*)kp;            // j-lo, ks0
    KB[1] = *(const short8*)(kp + 32);     // j-lo, ks1
    KB[2] = *(const short8*)(kp + 1024);   // j-hi (+16 rows), ks0
    KB[3] = *(const short8*)(kp + 1024+32);// j-hi, ks1
  };
  // V-frag loader: rows d = wn*32 + nf*16 + l15, cols j = jt*64 + l4*8 + ks*32
  auto loadV = [&](short8* VF, int jt){
    const u16* vp = vt_p + ((size_t)(wn*32 + l15))*2048 + jt*64 + l4*8;
    VF[0] = *(const short8*)vp;                 // nf0 ks0
    VF[1] = *(const short8*)(vp + 32);          // nf0 ks1
    VF[2] = *(const short8*)(vp + 16*2048);     // nf1 ks0
    VF[3] = *(const short8*)(vp + 16*2048+32);  // nf1 ks1
  };
  auto qkmma = [&](const short8* KB, f32x4 (&ZF)[4][2], const short8 (&QF)[4][2]){
#pragma unroll
    for (int mi=0;mi<4;++mi){
      ZF[mi][0] = MFMA(QF[mi][0], KB[0], ZF[mi][0]);
      ZF[mi][0] = MFMA(QF[mi][1], KB[1], ZF[mi][0]);
      ZF[mi][1] = MFMA(QF[mi][0], KB[2], ZF[mi][1]);
      ZF[mi][1] = MFMA(QF[mi][1], KB[3], ZF[mi][1]);
    }
  };

  // Q fragments resident in registers (scaled by 0.125*log2e, RoPE applied)
  short8 qhf[4][2];
#pragma unroll
  for (int mi=0;mi<4;++mi)
#pragma unroll
    for (int ks=0;ks<2;++ks)
      qhf[mi][ks] = *(const short8*)&qh_p[(size_t)(m0 + wm*64 + mi*16 + l15)*64 + l4*8 + ks*32];

  float lsum[4][4];
#pragma unroll
  for (int mi=0;mi<4;++mi)
#pragma unroll
    for (int r=0;r<4;++r) lsum[mi][r] = 0.f;

  // ---- pass 1: row sums of exp2(z'), barrier-free streaming ----
  auto p1body = [&](int jt, const short8* KB){
    f32x4 zf[4][2];
#pragma unroll
    for (int mi=0;mi<4;++mi){ zf[mi][0]=z4; zf[mi][1]=z4; }
    qkmma(KB, zf, qhf);
#pragma unroll
    for (int mi=0;mi<4;++mi)
#pragma unroll
      for (int r=0;r<4;++r){
        float p = exp2f(fminf(zf[mi][0][r], 80.f)) + exp2f(fminf(zf[mi][1][r], 80.f));
        p += __shfl_xor(p, 1, 64);
        p += __shfl_xor(p, 2, 64);
        p += __shfl_xor(p, 4, 64);
        p += __shfl_xor(p, 8, 64);
        lsum[mi][r] += p;
      }
  };
  {
    short8 kbA[4], kbB[4];
    loadK(kbA, 0);
    for (int jt = 0; jt < 32; jt += 2){
      loadK(kbB, (jt+1)&31);
      p1body(jt, kbA);
      loadK(kbA, (jt+2)&31);
      p1body(jt+1, kbB);
    }
  }

  if (l15 == 0){
#pragma unroll
    for (int mi=0;mi<4;++mi)
#pragma unroll
      for (int r=0;r<4;++r)
        lpart[wn][wm*64 + mi*16 + l4*4 + r] = lsum[mi][r];
  }
  __syncthreads();
  if (tid < 128) invl[tid] = 1.0f / (lpart[0][tid] + lpart[1][tid]);
  __syncthreads();

  // hoist this thread's 16 row-reciprocals into registers
  float ilr[4][4];
#pragma unroll
  for (int mi=0;mi<4;++mi)
#pragma unroll
    for (int r=0;r<4;++r) ilr[mi][r] = invl[wm*64 + mi*16 + l4*4 + r];

  // ---- pass 2: same z', w->WL(bf16)+wout(fp32 from regs), PV; 1 barrier/iter ----
  f32x4 oacc[4][2];
#pragma unroll
  for (int mi=0;mi<4;++mi){ oacc[mi][0]=z4; oacc[mi][1]=z4; }

  const size_t woutb = (bh*2048 + (size_t)m0)*2048;

  auto p2body = [&](int jt, const short8* KBcur, short8* KBnext, u16* WLc){
    short8 vf[4];
    loadV(vf, jt);
    loadK(KBnext, (jt+1)&31);
    f32x4 zf[4][2];
#pragma unroll
    for (int mi=0;mi<4;++mi){ zf[mi][0]=z4; zf[mi][1]=z4; }
    qkmma(KBcur, zf, qhf);
#pragma unroll
    for (int mi=0;mi<4;++mi)
#pragma unroll
      for (int r=0;r<4;++r){
        int rowl = wm*64 + mi*16 + l4*4 + r;
        float il = ilr[mi][r];
        float w0 = exp2f(fminf(zf[mi][0][r], 80.f)) * il;
        float w1 = exp2f(fminf(zf[mi][1][r], 80.f)) * il;
        WLc[rowl*LDP + wn*32 + l15]      = f2bf(w0);
        WLc[rowl*LDP + wn*32 + 16 + l15] = f2bf(w1);
        size_t gr = woutb + (size_t)rowl*2048 + jt*64;
        wout[gr + wn*32 + l15]      = w0;
        wout[gr + wn*32 + 16 + l15] = w1;
      }
    LGKM0; SBAR;
#pragma unroll
    for (int ks=0;ks<2;++ks){
      const int ko = l4*8 + ks*32;
      short8 aw[4];
#pragma unroll
      for (int mi=0;mi<4;++mi) aw[mi] = *(const short8*)&WLc[(wm*64 + mi*16 + l15)*LDP + ko];
#pragma unroll
      for (int mi=0;mi<4;++mi){
        oacc[mi][0] = MFMA(aw[mi], vf[0 + ks], oacc[mi][0]);
        oacc[mi][1] = MFMA(aw[mi], vf[2 + ks], oacc[mi][1]);
      }
    }
  };
  {
    short8 kbA[4], kbB[4];
    loadK(kbA, 0);
    for (int jt = 0; jt < 32; jt += 2){
      p2body(jt,   kbA, kbB, WL);
      p2body(jt+1, kbB, kbA, WL + 128*LDP);
    }
  }

#pragma unroll
  for (int mi=0;mi<4;++mi)
#pragma unroll
    for (int nf=0;nf<2;++nf)
#pragma unroll
      for (int r=0;r<4;++r){
        int rowl = wm*64 + mi*16 + l4*4 + r;
        int d = wn*32 + nf*16 + l15;
        aout[((size_t)(b*2048 + m0 + rowl)*16 + h)*64 + d] = f2bf(oacc[mi][nf][r]);
      }
}

// ---------------- output projection: out0 = attn_out @ Wo^T + bo ----------------
__global__ __launch_bounds__(256, 2) void k_oproj(
    const u16* __restrict__ A_g, const u16* __restrict__ W_g,
    const float* __restrict__ bias, float* __restrict__ out0)
{
  __shared__ __align__(16) u16 smem[4*TILE];
  const int n0 = blockIdx.x * 128, m0 = blockIdx.y * 128;
  const int tid = threadIdx.x, lane = tid & 63, wv = tid >> 6;
  const int wm = wv >> 1, wn = wv & 1, l15 = lane & 15, l4 = lane >> 4;
  const f32x4 z4 = {0.f,0.f,0.f,0.f};
  f32x4 acc[4][4];
#pragma unroll
  for (int i=0;i<4;++i)
#pragma unroll
    for (int j=0;j<4;++j) acc[i][j] = z4;

  auto stageAB = [&](int kt, int buf){
    u16* Ab = smem + buf*TILE;
    u16* Bb = smem + (2+buf)*TILE;
#pragma unroll
    for (int t = 0; t < 4; ++t){
      int r0 = (wv*4 + t)*8;
      stage8(&A_g[(size_t)(m0+r0)*1024 + kt*64], 1024, Ab, r0);
      stage8(&W_g[(size_t)(n0+r0)*1024 + kt*64], 1024, Bb, r0);
    }
  };

  stageAB(0, 0);
  VMCNT0; SBAR;
  for (int kt = 0; kt < 16; ++kt){
    const int cur = kt & 1;
    if (kt < 15) stageAB(kt+1, cur^1);
    const u16* Ac = smem + cur*TILE;
    const u16* Bc = smem + (2+cur)*TILE;
#pragma unroll
    for (int ks = 0; ks < 2; ++ks){
      const int ksg = l4 + ks*4;
      short8 ah[4], bhh[4];
#pragma unroll
      for (int mi=0;mi<4;++mi) ah[mi] = *(const short8*)&Ac[SW(wm*64+mi*16+l15, ksg)];
#pragma unroll
      for (int nf=0;nf<4;++nf) bhh[nf] = *(const short8*)&Bc[SW(wn*64+nf*16+l15, ksg)];
#pragma unroll
      for (int mi=0;mi<4;++mi)
#pragma unroll
        for (int nf=0;nf<4;++nf)
          acc[mi][nf] = MFMA(ah[mi], bhh[nf], acc[mi][nf]);
    }
    VMCNT0; SBAR;
  }
#pragma unroll
  for (int mi=0;mi<4;++mi)
#pragma unroll
    for (int nf=0;nf<4;++nf)
#pragma unroll
      for (int r=0;r<4;++r){
        int rowl = wm*64 + mi*16 + l4*4 + r;
        int coll = wn*64 + nf*16 + l15;
        out0[(size_t)(m0+rowl)*1024 + n0 + coll] = acc[mi][nf][r] + bias[n0+coll];
      }
}

// ---------------- launcher ----------------
extern "C" void kernel_launch(void* const* d_in, const int* in_sizes, int n_in,
                              void* d_out, int out_size, void* d_ws, size_t ws_size,
                              hipStream_t stream) {
  const float* query = (const float*)d_in[0];
  const float* key   = (const float*)d_in[1];
  const float* value = (const float*)d_in[2];
  const float* Wq = (const float*)d_in[3]; const float* bq = (const float*)d_in[4];
  const float* Wk = (const float*)d_in[5]; const float* bk = (const float*)d_in[6];
  const float* Wv = (const float*)d_in[7]; const float* bv = (const float*)d_in[8];
  const float* Wo = (const float*)d_in[9]; const float* bo = (const float*)d_in[10];

  float* out0 = (float*)d_out;                     // output (B,S,E), fp32
  float* out1 = out0 + (size_t)4096*1024;          // attn_weights (B,H,S,S), fp32

  char* cur = (char*)d_ws;
  auto take = [&](size_t bytes)->void*{
    void* p = (void*)cur; cur += (bytes + 255) & ~(size_t)255; return p;
  };
  u16* query_hi = (u16*)take(8388608);
  u16* key_hi   = (u16*)take(8388608);
  u16* value_hi = (u16*)take(8388608);
  u16* Wq_hi = (u16*)take(2097152);
  u16* Wk_hi = (u16*)take(2097152);
  u16* Wv_hi = (u16*)take(2097152);
  u16* Wo_hi = (u16*)take(2097152);
  u16* q_hi = (u16*)take(8388608);
  u16* k_hi = (u16*)take(8388608);
  u16* vT   = (u16*)take(8388608);
  u16* attn_o = (u16*)take(8388608);
  float* cs = (float*)take(524288);

  PrepArgs pa;
  pa.src[0]=query; pa.dst[0]=query_hi; pa.n4[0]=1048576;
  pa.src[1]=key;   pa.dst[1]=key_hi;   pa.n4[1]=1048576;
  pa.src[2]=value; pa.dst[2]=value_hi; pa.n4[2]=1048576;
  pa.src[3]=Wq;    pa.dst[3]=Wq_hi;    pa.n4[3]=262144;
  pa.src[4]=Wk;    pa.dst[4]=Wk_hi;    pa.n4[4]=262144;
  pa.src[5]=Wv;    pa.dst[5]=Wv_hi;    pa.n4[5]=262144;
  pa.src[6]=Wo;    pa.dst[6]=Wo_hi;    pa.n4[6]=262144;
  pa.cs = cs;
  k_prep<<<dim3(512,8), 256, 0, stream>>>(pa);

  k_projqkv<<<dim3(24,32), 256, 0, stream>>>(query_hi, key_hi, value_hi,
                                             Wq_hi, Wk_hi, Wv_hi,
                                             bq, bk, bv, cs,
                                             q_hi, k_hi, vT);

  k_attn<<<512, 256, 0, stream>>>(q_hi, k_hi, vT, out1, attn_o);

  k_oproj<<<dim3(8,32), 256, 0, stream>>>(attn_o, Wo_hi, bo, out0);
}